// Round 9
// baseline (281.328 us; speedup 1.0000x reference)
//
#include <hip/hip_runtime.h>
#include <math.h>

namespace {

constexpr int Bn = 8;
constexpr int Sn = 1024;
constexpr int Dn = 256;
constexpr int Mn = Bn * Sn;    // 8192 rows
constexpr int L  = 32;         // chunk length
constexpr int NSEG = Sn / L;   // 32 chunks

__device__ float g_den[Bn * Sn];   // raw n·q per (b,t); clamp applied in out_gemm

__device__ __forceinline__ float sigmoidf_(float x) {
    return 1.0f / (1.0f + __expf(-x));
}

// 16-value split butterfly over 64 lanes (HW-validated in r7).
// Result: lane L holds sum of value id=(L>>2)&15.
__device__ __forceinline__ void multi_reduce16(float v[16], int lane) {
    {   const bool hi = (lane & 32) != 0;
        #pragma unroll
        for (int i = 0; i < 8; ++i) {
            const float send = hi ? v[i] : v[i + 8];
            const float recv = __shfl_xor(send, 32, 64);
            v[i] = (hi ? v[i + 8] : v[i]) + recv;
        } }
    {   const bool hi = (lane & 16) != 0;
        #pragma unroll
        for (int i = 0; i < 4; ++i) {
            const float send = hi ? v[i] : v[i + 4];
            const float recv = __shfl_xor(send, 16, 64);
            v[i] = (hi ? v[i + 4] : v[i]) + recv;
        } }
    {   const bool hi = (lane & 8) != 0;
        #pragma unroll
        for (int i = 0; i < 2; ++i) {
            const float send = hi ? v[i] : v[i + 2];
            const float recv = __shfl_xor(send, 8, 64);
            v[i] = (hi ? v[i + 2] : v[i]) + recv;
        } }
    {   const bool hi = (lane & 4) != 0;
        const float send = hi ? v[0] : v[1];
        const float recv = __shfl_xor(send, 4, 64);
        v[0] = (hi ? v[1] : v[0]) + recv;
    }
    v[0] += __shfl_xor(v[0], 2, 64);
    v[0] += __shfl_xor(v[0], 1, 64);
}

// ---------------------------------------------------------------------------
// Fused projection GEMM: Y_m = act_m(X @ W_m^T + b_m) for m in {q,k,f,i}
// 32x64 tile, BK=16 -> 1024 blocks (4/CU) for latency hiding.
// ---------------------------------------------------------------------------
__global__ __launch_bounds__(256, 4) void proj_gemm(
    const float* __restrict__ X,
    const float* __restrict__ W0, const float* __restrict__ b0,
    const float* __restrict__ W1, const float* __restrict__ b1,
    const float* __restrict__ W2, const float* __restrict__ b2,
    const float* __restrict__ W3, const float* __restrict__ b3,
    float* __restrict__ Y0, float* __restrict__ Y1,
    float* __restrict__ Y2, float* __restrict__ Y3)
{
    __shared__ float As[16][34];      // [k][m], M=32
    __shared__ float Bs[4][16][68];   // [mat][k][n], N=64

    const int tid = threadIdx.x;
    const int tx  = tid & 15;         // col group: 4 cols
    const int ty  = tid >> 4;         // row group: 2 rows (0..15)
    const int mb  = blockIdx.x * 32;
    const int nb  = blockIdx.y * 64;
    const int alr = tid >> 3;         // A row 0..31
    const int alk = (tid & 7) * 2;    // A k-offset 0,2,..,14
    const int blr = tid >> 2;         // B row 0..63
    const int blk = (tid & 3) * 4;    // B k-offset 0,4,8,12

    float acc[4][2][4];
    #pragma unroll
    for (int m = 0; m < 4; ++m)
        #pragma unroll
        for (int i = 0; i < 2; ++i)
            #pragma unroll
            for (int j = 0; j < 4; ++j) acc[m][i][j] = 0.0f;

    for (int k0 = 0; k0 < Dn; k0 += 16) {
        const float2 a  = *(const float2*)(X  + (size_t)(mb + alr) * Dn + k0 + alk);
        const float4 w0 = *(const float4*)(W0 + (size_t)(nb + blr) * Dn + k0 + blk);
        const float4 w1 = *(const float4*)(W1 + (size_t)(nb + blr) * Dn + k0 + blk);
        const float4 w2 = *(const float4*)(W2 + (size_t)(nb + blr) * Dn + k0 + blk);
        const float4 w3 = *(const float4*)(W3 + (size_t)(nb + blr) * Dn + k0 + blk);
        __syncthreads();
        As[alk][alr]     = a.x;
        As[alk + 1][alr] = a.y;
        Bs[0][blk+0][blr] = w0.x; Bs[0][blk+1][blr] = w0.y; Bs[0][blk+2][blr] = w0.z; Bs[0][blk+3][blr] = w0.w;
        Bs[1][blk+0][blr] = w1.x; Bs[1][blk+1][blr] = w1.y; Bs[1][blk+2][blr] = w1.z; Bs[1][blk+3][blr] = w1.w;
        Bs[2][blk+0][blr] = w2.x; Bs[2][blk+1][blr] = w2.y; Bs[2][blk+2][blr] = w2.z; Bs[2][blk+3][blr] = w2.w;
        Bs[3][blk+0][blr] = w3.x; Bs[3][blk+1][blr] = w3.y; Bs[3][blk+2][blr] = w3.z; Bs[3][blk+3][blr] = w3.w;
        __syncthreads();

        #pragma unroll
        for (int kk = 0; kk < 16; ++kk) {
            const float2 av = *(const float2*)&As[kk][ty * 2];
            #pragma unroll
            for (int m = 0; m < 4; ++m) {
                const float4 bv = *(const float4*)&Bs[m][kk][tx * 4];
                const float bb[4] = {bv.x, bv.y, bv.z, bv.w};
                #pragma unroll
                for (int j = 0; j < 4; ++j) {
                    acc[m][0][j] = fmaf(av.x, bb[j], acc[m][0][j]);
                    acc[m][1][j] = fmaf(av.y, bb[j], acc[m][1][j]);
                }
            }
        }
    }

    const float4 bb0 = *(const float4*)(b0 + nb + tx * 4);
    const float4 bb1 = *(const float4*)(b1 + nb + tx * 4);
    const float4 bb2 = *(const float4*)(b2 + nb + tx * 4);
    const float4 bb3 = *(const float4*)(b3 + nb + tx * 4);

    #pragma unroll
    for (int i = 0; i < 2; ++i) {
        const size_t rowoff = (size_t)(mb + ty * 2 + i) * Dn + nb + tx * 4;
        float4 o;
        o.x = acc[0][i][0] + bb0.x; o.y = acc[0][i][1] + bb0.y;
        o.z = acc[0][i][2] + bb0.z; o.w = acc[0][i][3] + bb0.w;
        *(float4*)(Y0 + rowoff) = o;
        o.x = acc[1][i][0] + bb1.x; o.y = acc[1][i][1] + bb1.y;
        o.z = acc[1][i][2] + bb1.z; o.w = acc[1][i][3] + bb1.w;
        *(float4*)(Y1 + rowoff) = o;
        o.x = sigmoidf_(acc[2][i][0] + bb2.x); o.y = sigmoidf_(acc[2][i][1] + bb2.y);
        o.z = sigmoidf_(acc[2][i][2] + bb2.z); o.w = sigmoidf_(acc[2][i][3] + bb2.w);
        *(float4*)(Y2 + rowoff) = o;
        o.x = __expf(acc[3][i][0] + bb3.x); o.y = __expf(acc[3][i][1] + bb3.y);
        o.z = __expf(acc[3][i][2] + bb3.z); o.w = __expf(acc[3][i][3] + bb3.w);
        *(float4*)(Y3 + rowoff) = o;
    }
}

// ---------------------------------------------------------------------------
// Output GEMM: out = (num * invden) @ Wo^T + bo  (invden folded into A-load)
// 32x64 tile -> 1024 blocks (4/CU).
// ---------------------------------------------------------------------------
__global__ __launch_bounds__(256, 4) void out_gemm(
    const float* __restrict__ X, const float* __restrict__ W,
    const float* __restrict__ bias, float* __restrict__ Y)
{
    __shared__ float As[16][34];
    __shared__ float Bs[16][68];

    const int tid = threadIdx.x;
    const int tx  = tid & 15;
    const int ty  = tid >> 4;
    const int mb  = blockIdx.x * 32;
    const int nb  = blockIdx.y * 64;
    const int alr = tid >> 3;
    const int alk = (tid & 7) * 2;
    const int blr = tid >> 2;
    const int blk = (tid & 3) * 4;

    const float dn   = g_den[mb + alr];
    const float invd = 1.0f / fmaxf(fabsf(dn), 1.0f);

    float acc[2][4];
    #pragma unroll
    for (int i = 0; i < 2; ++i)
        #pragma unroll
        for (int j = 0; j < 4; ++j) acc[i][j] = 0.0f;

    for (int k0 = 0; k0 < Dn; k0 += 16) {
        float2 a = *(const float2*)(X + (size_t)(mb + alr) * Dn + k0 + alk);
        const float4 w = *(const float4*)(W + (size_t)(nb + blr) * Dn + k0 + blk);
        a.x *= invd; a.y *= invd;
        __syncthreads();
        As[alk][alr]     = a.x;
        As[alk + 1][alr] = a.y;
        Bs[blk+0][blr] = w.x; Bs[blk+1][blr] = w.y; Bs[blk+2][blr] = w.z; Bs[blk+3][blr] = w.w;
        __syncthreads();

        #pragma unroll
        for (int kk = 0; kk < 16; ++kk) {
            const float2 av = *(const float2*)&As[kk][ty * 2];
            const float4 bv = *(const float4*)&Bs[kk][tx * 4];
            const float bb[4] = {bv.x, bv.y, bv.z, bv.w};
            #pragma unroll
            for (int j = 0; j < 4; ++j) {
                acc[0][j] = fmaf(av.x, bb[j], acc[0][j]);
                acc[1][j] = fmaf(av.y, bb[j], acc[1][j]);
            }
        }
    }

    const float4 bbv = *(const float4*)(bias + nb + tx * 4);
    #pragma unroll
    for (int i = 0; i < 2; ++i) {
        const size_t rowoff = (size_t)(mb + ty * 2 + i) * Dn + nb + tx * 4;
        float4 o;
        o.x = acc[i][0] + bbv.x; o.y = acc[i][1] + bbv.y;
        o.z = acc[i][2] + bbv.z; o.w = acc[i][3] + bbv.w;
        *(float4*)(Y + rowoff) = o;
    }
}

// ---------------------------------------------------------------------------
// gate_prep: per (chunk m, batch b), thread = r. Elementwise chunk scans:
//   G[τ,r] = Π_{u<=τ} f ;  Ṽ[τ,r] = i·v/G ;  Ñ[τ,r] = Σ i·k/G
//   Aend = G[L-1], un = Aend·Ñ[L-1]
// ---------------------------------------------------------------------------
__global__ __launch_bounds__(256) void gate_prep(
    const float* __restrict__ Pf, const float* __restrict__ Pi,
    const float* __restrict__ Pk, const float* __restrict__ Pq,
    float* __restrict__ Gc, float* __restrict__ Vt, float* __restrict__ Nt,
    float* __restrict__ Aend, float* __restrict__ un)
{
    const int m = blockIdx.x;
    const int b = blockIdx.y;
    const int r = threadIdx.x;
    const size_t base = (size_t)b * Sn * Dn + (size_t)m * L * Dn + r;

    float G = 1.0f, Nacc = 0.0f;
    #pragma unroll 4
    for (int t = 0; t < L; ++t) {
        const size_t off = base + (size_t)t * Dn;
        const float f  = Pf[off];
        const float iv = Pi[off];
        const float kv = Pk[off];
        const float vv = Pq[off];     // v = q projection (Wv unused)
        G *= f;
        const float rG = 1.0f / G;
        Gc[off] = G;
        Vt[off] = iv * vv * rG;
        Nacc = fmaf(iv * kv, rG, Nacc);
        Nt[off] = Nacc;
    }
    const size_t s = ((size_t)b * NSEG + m) * Dn + r;
    Aend[s] = G;
    un[s]   = G * Nacc;
}

// ---------------------------------------------------------------------------
// ut_gemm: UT[b,m][c,r] = Aend[r] * Σ_σ K[σ,c]·Ṽ[σ,r]   (chunk from-zero state,
// stored transposed). Grid (Bn*NSEG, 16 tiles of 64x64). K-dim = L = 32.
// ---------------------------------------------------------------------------
__global__ __launch_bounds__(256) void ut_gemm(
    const float* __restrict__ Pk, const float* __restrict__ Vt,
    const float* __restrict__ Aend, float* __restrict__ UT)
{
    __shared__ float As[L][68];   // K^T tile: As[σ][c]
    __shared__ float Bs[L][68];   // Ṽ tile:  Bs[σ][r]

    const int bm   = blockIdx.x;           // b*NSEG + m
    const int tile = blockIdx.y;
    const int cb   = (tile >> 2) * 64;
    const int rb   = (tile & 3) * 64;
    const int b    = bm >> 5;
    const int m    = bm & 31;
    const size_t kb = (size_t)b * Sn * Dn + (size_t)m * L * Dn;
    const int tid = threadIdx.x;

    #pragma unroll
    for (int n = 0; n < 8; ++n) {
        const int e  = n * 256 + tid;
        const int sg = e >> 6;
        const int cc = e & 63;
        As[sg][cc] = Pk[kb + (size_t)sg * Dn + cb + cc];
        Bs[sg][cc] = Vt[kb + (size_t)sg * Dn + rb + cc];
    }
    __syncthreads();

    const int tx = tid & 15;
    const int ty = tid >> 4;
    float acc[4][4];
    #pragma unroll
    for (int i = 0; i < 4; ++i)
        #pragma unroll
        for (int j = 0; j < 4; ++j) acc[i][j] = 0.0f;

    #pragma unroll
    for (int sg = 0; sg < L; ++sg) {
        const float4 a4 = *(const float4*)&As[sg][ty * 4];
        const float4 b4 = *(const float4*)&Bs[sg][tx * 4];
        const float aa[4] = {a4.x, a4.y, a4.z, a4.w};
        const float bb[4] = {b4.x, b4.y, b4.z, b4.w};
        #pragma unroll
        for (int i = 0; i < 4; ++i)
            #pragma unroll
            for (int j = 0; j < 4; ++j)
                acc[i][j] = fmaf(aa[i], bb[j], acc[i][j]);
    }

    const float4 g4 = *(const float4*)(Aend + (size_t)bm * Dn + rb + tx * 4);
    float* ub = UT + (size_t)bm * Dn * Dn;
    #pragma unroll
    for (int i = 0; i < 4; ++i) {
        float4 o;
        o.x = acc[i][0] * g4.x; o.y = acc[i][1] * g4.y;
        o.z = acc[i][2] * g4.z; o.w = acc[i][3] * g4.w;
        *(float4*)(ub + (size_t)(cb + ty * 4 + i) * Dn + rb + tx * 4) = o;
    }
}

// ---------------------------------------------------------------------------
// compose: sequential over chunks (32 steps, elementwise).
//  gx<64 : CinT[b,m][c,r] = carry state before chunk m (transposed layout).
//  gx==64: nin[b,m][r] likewise from (Aend, un).
// ---------------------------------------------------------------------------
__global__ __launch_bounds__(256) void compose(
    const float* __restrict__ UT, const float* __restrict__ Aend,
    const float* __restrict__ un,
    float* __restrict__ CinT, float* __restrict__ nin)
{
    const int gx = blockIdx.x;
    const int b  = blockIdx.y;
    const int tid = threadIdx.x;

    if (gx == 64) {
        const int r = tid;
        float acc = 0.0f;
        for (int m = 0; m < NSEG; ++m) {
            const size_t s = ((size_t)b * NSEG + m) * Dn + r;
            nin[s] = acc;
            acc = fmaf(Aend[s], acc, un[s]);
        }
        return;
    }

    const int id = gx * 256 + tid;       // 0..16383
    const int c  = id >> 6;
    const int r4 = (id & 63) * 4;

    float4 acc = make_float4(0.f, 0.f, 0.f, 0.f);
    for (int m = 0; m < NSEG; ++m) {
        const size_t bm  = (size_t)b * NSEG + m;
        const size_t idx = bm * Dn * Dn + (size_t)c * Dn + r4;
        *(float4*)(CinT + idx) = acc;
        const float4 a4 = *(const float4*)(Aend + bm * Dn + r4);
        const float4 u4 = *(const float4*)(UT + idx);
        acc.x = fmaf(a4.x, acc.x, u4.x);
        acc.y = fmaf(a4.y, acc.y, u4.y);
        acc.z = fmaf(a4.z, acc.z, u4.z);
        acc.w = fmaf(a4.w, acc.w, u4.w);
    }
}

// ---------------------------------------------------------------------------
// s_gemm: S[b,m][τ,σ] = k_σ·q_τ for σ<=τ else 0.  Grid (NSEG, Bn), 256 thr,
// 4 outputs/thread (τ = tid/8, σ4 = (tid%8)*4).
// ---------------------------------------------------------------------------
__global__ __launch_bounds__(256) void s_gemm(
    const float* __restrict__ Pk, const float* __restrict__ Pq,
    float* __restrict__ Ssm)
{
    const int m = blockIdx.x;
    const int b = blockIdx.y;
    const size_t qb = (size_t)b * Sn * Dn + (size_t)m * L * Dn;
    const int tid = threadIdx.x;
    const int tau = tid >> 3;
    const int s4  = (tid & 7) * 4;

    float a0 = 0.f, a1 = 0.f, a2 = 0.f, a3 = 0.f;
    #pragma unroll 4
    for (int c = 0; c < Dn; c += 4) {
        const float4 q4 = *(const float4*)(Pq + qb + (size_t)tau * Dn + c);
        const float4 k0 = *(const float4*)(Pk + qb + (size_t)(s4 + 0) * Dn + c);
        const float4 k1 = *(const float4*)(Pk + qb + (size_t)(s4 + 1) * Dn + c);
        const float4 k2 = *(const float4*)(Pk + qb + (size_t)(s4 + 2) * Dn + c);
        const float4 k3 = *(const float4*)(Pk + qb + (size_t)(s4 + 3) * Dn + c);
        a0 += q4.x*k0.x + q4.y*k0.y + q4.z*k0.z + q4.w*k0.w;
        a1 += q4.x*k1.x + q4.y*k1.y + q4.z*k1.z + q4.w*k1.w;
        a2 += q4.x*k2.x + q4.y*k2.y + q4.z*k2.z + q4.w*k2.w;
        a3 += q4.x*k3.x + q4.y*k3.y + q4.z*k3.z + q4.w*k3.w;
    }
    float* out = Ssm + ((size_t)b * NSEG + m) * L * L + (size_t)tau * L + s4;
    out[0] = (s4 + 0 <= tau) ? a0 : 0.0f;
    out[1] = (s4 + 1 <= tau) ? a1 : 0.0f;
    out[2] = (s4 + 2 <= tau) ? a2 : 0.0f;
    out[3] = (s4 + 3 <= tau) ? a3 : 0.0f;
}

// ---------------------------------------------------------------------------
// num_gemm: Pnum[τ,r] = G[τ,r]·( Σ_σ S[τ,σ]Ṽ[σ,r] + Σ_c Q[τ,c]CinT[c,r] )
// Grid (2, NSEG, Bn): 32τ x 128r per block. 256 thr: tx=tid&31 -> r4,
// ty=tid>>5 -> 4 τ's.
// ---------------------------------------------------------------------------
__global__ __launch_bounds__(256) void num_gemm(
    const float* __restrict__ Pq, const float* __restrict__ Vt,
    const float* __restrict__ Gc, const float* __restrict__ Ssm,
    const float* __restrict__ CinT, float* __restrict__ Pnum)
{
    __shared__ float Sld[L][33];
    __shared__ float Qld[L][257];

    const int rb = blockIdx.x * 128;
    const int m  = blockIdx.y;
    const int b  = blockIdx.z;
    const size_t qb = (size_t)b * Sn * Dn + (size_t)m * L * Dn;
    const size_t ub = ((size_t)b * NSEG + m) * Dn * Dn;
    const size_t sb = ((size_t)b * NSEG + m) * L * L;
    const int tid = threadIdx.x;

    #pragma unroll
    for (int n = 0; n < 4; ++n) {
        const int e = n * 256 + tid;
        Sld[e >> 5][e & 31] = Ssm[sb + e];
    }
    #pragma unroll
    for (int n = 0; n < L; ++n)
        Qld[n][tid] = Pq[qb + (size_t)n * Dn + tid];
    __syncthreads();

    const int tx = tid & 31;
    const int ty = tid >> 5;
    const int r4 = rb + tx * 4;
    const int t4 = ty * 4;

    float4 acc[4];
    #pragma unroll
    for (int i = 0; i < 4; ++i) acc[i] = make_float4(0.f, 0.f, 0.f, 0.f);

    // phase 1: S @ Ṽ  (K = 32)
    #pragma unroll 4
    for (int sg = 0; sg < L; ++sg) {
        const float4 v4 = *(const float4*)(Vt + qb + (size_t)sg * Dn + r4);
        #pragma unroll
        for (int i = 0; i < 4; ++i) {
            const float s = Sld[t4 + i][sg];
            acc[i].x = fmaf(s, v4.x, acc[i].x);
            acc[i].y = fmaf(s, v4.y, acc[i].y);
            acc[i].z = fmaf(s, v4.z, acc[i].z);
            acc[i].w = fmaf(s, v4.w, acc[i].w);
        }
    }

    // phase 2: Q @ Cin^T  (K = 256)
    #pragma unroll 8
    for (int c = 0; c < Dn; ++c) {
        const float4 ct = *(const float4*)(CinT + ub + (size_t)c * Dn + r4);
        #pragma unroll
        for (int i = 0; i < 4; ++i) {
            const float q = Qld[t4 + i][c];
            acc[i].x = fmaf(q, ct.x, acc[i].x);
            acc[i].y = fmaf(q, ct.y, acc[i].y);
            acc[i].z = fmaf(q, ct.z, acc[i].z);
            acc[i].w = fmaf(q, ct.w, acc[i].w);
        }
    }

    #pragma unroll
    for (int i = 0; i < 4; ++i) {
        const size_t off = qb + (size_t)(t4 + i) * Dn + r4;
        const float4 g4 = *(const float4*)(Gc + off);
        float4 o;
        o.x = acc[i].x * g4.x; o.y = acc[i].y * g4.y;
        o.z = acc[i].z * g4.z; o.w = acc[i].w * g4.w;
        *(float4*)(Pnum + off) = o;
    }
}

// ---------------------------------------------------------------------------
// den_kernel: g_den[b,t] = Σ_r q[t,r]·G[t,r]·(nin[m,r] + Ñ[t,r]),  m = t/L.
// Grid (8, Bn): 128 τ per block, 32 per wave, batched 16 into multi_reduce16.
// ---------------------------------------------------------------------------
__global__ __launch_bounds__(256) void den_kernel(
    const float* __restrict__ Pq, const float* __restrict__ Gc,
    const float* __restrict__ Nt, const float* __restrict__ nin)
{
    const int gx = blockIdx.x;
    const int b  = blockIdx.y;
    const int tid  = threadIdx.x;
    const int lane = tid & 63;
    const int wv   = tid >> 6;
    const int c4   = lane * 4;

    for (int batch = 0; batch < 2; ++batch) {
        const int tbase = gx * 128 + wv * 32 + batch * 16;
        float p[16];
        #pragma unroll
        for (int j = 0; j < 16; ++j) {
            const int t = tbase + j;
            const int m = t >> 5;
            const size_t off = (size_t)b * Sn * Dn + (size_t)t * Dn + c4;
            const float4 q4 = *(const float4*)(Pq + off);
            const float4 g4 = *(const float4*)(Gc + off);
            const float4 n4 = *(const float4*)(Nt + off);
            const float4 i4 = *(const float4*)(nin + ((size_t)b * NSEG + m) * Dn + c4);
            p[j] = q4.x * g4.x * (i4.x + n4.x)
                 + q4.y * g4.y * (i4.y + n4.y)
                 + q4.z * g4.z * (i4.z + n4.z)
                 + q4.w * g4.w * (i4.w + n4.w);
        }
        multi_reduce16(p, lane);
        if ((lane & 3) == 0)
            g_den[b * Sn + tbase + ((lane >> 2) & 15)] = p[0];
    }
}

} // anonymous namespace

extern "C" void kernel_launch(void* const* d_in, const int* in_sizes, int n_in,
                              void* d_out, int out_size, void* d_ws, size_t ws_size,
                              hipStream_t stream)
{
    const float* x  = (const float*)d_in[0];
    const float* Wq = (const float*)d_in[1];  const float* bq = (const float*)d_in[2];
    const float* Wk = (const float*)d_in[3];  const float* bk = (const float*)d_in[4];
    // d_in[5]=Wv, d_in[6]=bv unused (reference uses W_q for v)
    const float* Wf = (const float*)d_in[7];  const float* bf = (const float*)d_in[8];
    const float* Wi = (const float*)d_in[9];  const float* bi = (const float*)d_in[10];
    const float* Wo = (const float*)d_in[11]; const float* bo = (const float*)d_in[12];
    float* out = (float*)d_out;

    float* ws = (float*)d_ws;
    const size_t sz = (size_t)Mn * Dn;            // 2,097,152 floats (8 MB)
    float* Pq = ws;
    float* Pk = ws + sz;
    float* Pf = ws + 2 * sz;
    float* Pi = ws + 3 * sz;
    float* Pn = ws + 4 * sz;                      // numerators
    float* Gc = ws + 5 * sz;                      // G cumprod  [b,t,r]
    float* Vt = ws + 6 * sz;                      // Ṽ          [b,t,r]
    float* Nt = ws + 7 * sz;                      // Ñ cumsum   [b,t,r]
    float* UT   = ws + 8 * sz;                    // [b,m][c][r]  8*sz
    float* CinT = ws + 16 * sz;                   // [b,m][c][r]  8*sz
    float* Ssm  = ws + 24 * sz;                   // [b,m][τ][σ]  262144
    float* Aend = Ssm + (size_t)Bn * NSEG * L * L;
    float* un   = Aend + (size_t)Bn * NSEG * Dn;
    float* nin  = un   + (size_t)Bn * NSEG * Dn;

    proj_gemm<<<dim3(Mn / 32, Dn / 64), 256, 0, stream>>>(
        x, Wq, bq, Wk, bk, Wf, bf, Wi, bi, Pq, Pk, Pf, Pi);

    gate_prep<<<dim3(NSEG, Bn), 256, 0, stream>>>(
        Pf, Pi, Pk, Pq, Gc, Vt, Nt, Aend, un);

    ut_gemm<<<dim3(Bn * NSEG, 16), 256, 0, stream>>>(Pk, Vt, Aend, UT);

    compose<<<dim3(65, Bn), 256, 0, stream>>>(UT, Aend, un, CinT, nin);

    s_gemm<<<dim3(NSEG, Bn), 256, 0, stream>>>(Pk, Pq, Ssm);

    num_gemm<<<dim3(2, NSEG, Bn), 256, 0, stream>>>(
        Pq, Vt, Gc, Ssm, CinT, Pn);

    den_kernel<<<dim3(8, Bn), 256, 0, stream>>>(Pq, Gc, Nt, nin);

    out_gemm<<<dim3(Mn / 32, Dn / 64), 256, 0, stream>>>(Pn, Wo, bo, out);
}